// Round 4
// baseline (483.406 us; speedup 1.0000x reference)
//
#include <hip/hip_runtime.h>

// PDELoss fused, wave-autonomous. R4: spill-free high occupancy.
// Each 64-lane wave owns one (image, 8-row strip); thread = 4 cols (float4).
// Coefficients kept as 18 block-uniform scalars (SGPRs): gs = L + invr*D with
// L,D two 9-tap stencil accumulators — replaces R2/R3's 36-VGPR c4[] array.
// __launch_bounds__(256,6): ~85 VGPR cap, fits ~60-reg live state, no scratch.
// No LDS/barriers in hot loop; pred halo via prefetched float2 (L1 hit);
// 1-iteration prefetch distance on pred & rhs; 2 shuffles/iter (gs halo only).

__global__ __launch_bounds__(256, 6)
void pde_loss_kernel(const float* __restrict__ pred,   // [B,256,256]
                     const float* __restrict__ rhs,    // [B,254,254]
                     const float* __restrict__ KL,     // [B,3,3]
                     const float* __restrict__ KD,     // [B,3,3]
                     const float* __restrict__ RR,     // [B,256,256] (col-only)
                     const float* __restrict__ ZZ,     // [B,256,256] (row-only)
                     float* __restrict__ out,
                     float inv_n)
{
    constexpr int H = 256, W = 256, OH = 254, OW = 254;
    const int tid = threadIdx.x;
    const int l   = tid & 63;          // lane
    const int wv  = tid >> 6;          // wave in block
    const int b   = blockIdx.x >> 3;   // image (8 blocks/image, block-uniform)
    const int strip = (blockIdx.x & 7) * 4 + wv;   // 32 strips of 8 rows
    const int o0 = strip * 8;
    const int o1 = (o0 + 8 < OH) ? (o0 + 8) : OH;  // last strip: 6 rows

    const size_t ib = (size_t)b * H * W;
    const float* predb = pred + ib;
    const float* rhsb  = rhs + (size_t)b * OH * OW;

    const float hr  = RR[ib + W + 2] - RR[ib + W + 1];
    const float hz  = ZZ[ib + 2 * W + 1] - ZZ[ib + W + 1];
    const float hr2 = hr * hr, hz2 = hz * hz;
    const float s   = -2.0f * (hr2 + hz2) / (hr2 * hz2);

    // Block-uniform folded kernels -> SGPRs (address is block-uniform)
    float kls[9], kds[9];
#pragma unroll
    for (int t = 0; t < 9; ++t) {
        kls[t] = KL[b * 9 + t] * s;
        kds[t] = KD[b * 9 + t] * s;
    }

    // Per-lane 1/r for the 4 owned output columns (vector state: 4 VGPRs)
    const int c0 = 4 * l;
    const int hcol = (c0 + 4 < W) ? (c0 + 4) : (W - 2);  // halo col (lane63 unused)
    float4 invr;
    invr.x = 1.0f / RR[ib + W + (c0 + 1)];
    invr.y = 1.0f / RR[ib + W + (c0 + 2)];
    invr.z = 1.0f / RR[ib + W + (c0 + 3)];
    invr.w = 1.0f / RR[ib + W + ((c0 + 4 < W) ? (c0 + 4) : (W - 1))];

    // Prologue: rolling pred rows g0..g0+2 (pa,pb,pc) + halo float2s
    const int g0 = o0 - 1;
    float4 pa = make_float4(0.f, 0.f, 0.f, 0.f), pb, pc;
    float2 ha = make_float2(0.f, 0.f), hb, hc;
    if (g0 >= 0) {
        pa = *(const float4*)(predb + (size_t)g0 * W + c0);
        ha = *(const float2*)(predb + (size_t)g0 * W + hcol);
    }
    pb = *(const float4*)(predb + (size_t)(g0 + 1) * W + c0);
    hb = *(const float2*)(predb + (size_t)(g0 + 1) * W + hcol);
    pc = *(const float4*)(predb + (size_t)(g0 + 2) * W + c0);
    hc = *(const float2*)(predb + (size_t)(g0 + 2) * W + hcol);

    float4 ghA = make_float4(0.f, 0.f, 0.f, 0.f);
    float4 ghB = make_float4(0.f, 0.f, 0.f, 0.f);
    float2 rc0 = make_float2(0.f, 0.f), rc1 = make_float2(0.f, 0.f);
    float acc = 0.0f;

    for (int g = g0; g <= o1; ++g) {
        // --- prefetch pred row g+3 + halo (consumed next iteration) ---
        float4 pn = make_float4(0.f, 0.f, 0.f, 0.f);
        float2 hn = make_float2(0.f, 0.f);
        const int rowp = g + 3;
        if (rowp < H && rowp <= o1 + 2) {
            pn = *(const float4*)(predb + (size_t)rowp * W + c0);
            hn = *(const float2*)(predb + (size_t)rowp * W + hcol);
        }

        // --- prefetch rhs row g (consumed next iteration at emit i=g) ---
        float2 rn0 = make_float2(0.f, 0.f), rn1 = make_float2(0.f, 0.f);
        if (g >= o0 && g < o1) {
            const float* rrow = rhsb + (size_t)g * OW + c0;
            rn0 = *(const float2*)rrow;
            if (c0 + 2 < OW) rn1 = *(const float2*)(rrow + 2);
        }

        // --- GS_ope row g: gs = L + invr * D, two 9-tap stencils ---
        float4 gs = make_float4(0.f, 0.f, 0.f, 0.f);
        if ((unsigned)g < (unsigned)OH) {
            float4 L = make_float4(0.f, 0.f, 0.f, 0.f);
            float4 D = make_float4(0.f, 0.f, 0.f, 0.f);
#define ROWC(p, h, t0)                                                   \
            L.x = fmaf(p.x, kls[t0], fmaf(p.y, kls[t0+1], fmaf(p.z, kls[t0+2], L.x))); \
            L.y = fmaf(p.y, kls[t0], fmaf(p.z, kls[t0+1], fmaf(p.w, kls[t0+2], L.y))); \
            L.z = fmaf(p.z, kls[t0], fmaf(p.w, kls[t0+1], fmaf(h.x, kls[t0+2], L.z))); \
            L.w = fmaf(p.w, kls[t0], fmaf(h.x, kls[t0+1], fmaf(h.y, kls[t0+2], L.w))); \
            D.x = fmaf(p.x, kds[t0], fmaf(p.y, kds[t0+1], fmaf(p.z, kds[t0+2], D.x))); \
            D.y = fmaf(p.y, kds[t0], fmaf(p.z, kds[t0+1], fmaf(p.w, kds[t0+2], D.y))); \
            D.z = fmaf(p.z, kds[t0], fmaf(p.w, kds[t0+1], fmaf(h.x, kds[t0+2], D.z))); \
            D.w = fmaf(p.w, kds[t0], fmaf(h.x, kds[t0+1], fmaf(h.y, kds[t0+2], D.w)));
            ROWC(pa, ha, 0)
            ROWC(pb, hb, 3)
            ROWC(pc, hc, 6)
#undef ROWC
            gs.x = fmaf(invr.x, D.x, L.x);
            gs.y = fmaf(invr.y, D.y, L.y);
            gs.z = fmaf(invr.z, D.z, L.z);
            gs.w = fmaf(invr.w, D.w, L.w);
            if (l == 63) { gs.z = 0.f; gs.w = 0.f; }   // cols 254,255 out of range
        }

        // --- horizontal [1,2,1]; halos via shfl (computed data) ---
        float up = __shfl(gs.w, l - 1, 64);
        const float dn = __shfl(gs.x, l + 1, 64);     // lane 63: garbage, unused
        if (l == 0) up = 0.f;
        float4 gh;
        gh.x = fmaf(2.f, gs.x, up   + gs.y);
        gh.y = fmaf(2.f, gs.y, gs.x + gs.z);
        gh.z = fmaf(2.f, gs.z, gs.y + gs.w);
        gh.w = fmaf(2.f, gs.w, gs.z + dn);

        // --- vertical [1,2,1]/16, emit row i = g-1, MSE accumulate ---
        const int i = g - 1;
        if (i >= o0 && i < o1) {
            const float smx = (ghA.x + 2.f * ghB.x + gh.x) * 0.0625f;
            const float smy = (ghA.y + 2.f * ghB.y + gh.y) * 0.0625f;
            const float smz = (ghA.z + 2.f * ghB.z + gh.z) * 0.0625f;
            const float smw = (ghA.w + 2.f * ghB.w + gh.w) * 0.0625f;
            const float dx = smx - rc0.x;
            const float dy = smy - rc0.y;
            float dz = smz - rc1.x;
            float dw = smw - rc1.y;
            if (c0 + 2 >= OW) { dz = 0.f; dw = 0.f; }   // lane 63 tail cols
            acc = fmaf(dx, dx, acc);
            acc = fmaf(dy, dy, acc);
            acc = fmaf(dz, dz, acc);
            acc = fmaf(dw, dw, acc);
        }

        // --- roll ---
        pa = pb; pb = pc; pc = pn;
        ha = hb; hb = hc; hc = hn;
        ghA = ghB; ghB = gh;
        rc0 = rn0; rc1 = rn1;
    }

    // wave reduce -> block reduce -> one atomic per block
#pragma unroll
    for (int off = 32; off > 0; off >>= 1)
        acc += __shfl_down(acc, off, 64);
    __shared__ float wsum[4];
    if (l == 0) wsum[wv] = acc;
    __syncthreads();
    if (tid == 0) {
        const float t = (wsum[0] + wsum[1]) + (wsum[2] + wsum[3]);
        atomicAdd(out, t * inv_n);
    }
}

extern "C" void kernel_launch(void* const* d_in, const int* in_sizes, int n_in,
                              void* d_out, int out_size, void* d_ws, size_t ws_size,
                              hipStream_t stream) {
    const float* pred = (const float*)d_in[0];
    const float* rhs  = (const float*)d_in[1];
    const float* KL   = (const float*)d_in[2];
    const float* KD   = (const float*)d_in[3];
    const float* RR   = (const float*)d_in[4];
    const float* ZZ   = (const float*)d_in[5];
    // d_in[6] = Gauss kernel [[1,2,1],[2,4,2],[1,2,1]]/16 — hardcoded, separable
    float* out = (float*)d_out;

    const int B = in_sizes[2] / 9;   // 256
    const float inv_n = 1.0f / ((float)B * 254.0f * 254.0f);

    hipMemsetAsync(out, 0, sizeof(float), stream);
    pde_loss_kernel<<<dim3(B * 8), dim3(256), 0, stream>>>(pred, rhs, KL, KD, RR, ZZ, out, inv_n);
}

// Round 5
// 228.237 us; speedup vs baseline: 2.1180x; 2.1180x over previous
//
#include <hip/hip_runtime.h>

// PDELoss fused, wave-autonomous. R5 = R2 kernel (52 VGPR, zero scratch,
// verified) with 8-row strips: 2048 blocks = 8192 waves = 32 waves/CU
// available. NO aggressive launch_bounds — (256,4) is the only config the
// allocator handled without catastrophic scratch spill (R3/R4 post-mortems).
// Each 64-lane wave owns one (image, 8-row strip); thread = 4 cols (float4).
// Per-lane folded coefs c4[9] (36 VGPR, 9 FMA/component); pred horizontal
// halo via __shfl; rolling 3-row register window; 1-iter prefetch distance.

__global__ __launch_bounds__(256, 4)
void pde_loss_kernel(const float* __restrict__ pred,   // [B,256,256]
                     const float* __restrict__ rhs,    // [B,254,254]
                     const float* __restrict__ KL,     // [B,3,3]
                     const float* __restrict__ KD,     // [B,3,3]
                     const float* __restrict__ RR,     // [B,256,256] (col-only)
                     const float* __restrict__ ZZ,     // [B,256,256] (row-only)
                     float* __restrict__ out,
                     float inv_n)
{
    constexpr int H = 256, W = 256, OH = 254, OW = 254;
    const int tid = threadIdx.x;
    const int l   = tid & 63;          // lane
    const int wv  = tid >> 6;          // wave in block
    const int b   = blockIdx.x >> 3;   // image (8 blocks/image)
    const int strip = (blockIdx.x & 7) * 4 + wv;   // 32 strips of 8 rows
    const int o0 = strip * 8;
    const int o1 = (o0 + 8 < OH) ? (o0 + 8) : OH;  // last strip: 6 rows

    const size_t ib = (size_t)b * H * W;
    const float* predb = pred + ib;
    const float* rhsb  = rhs + (size_t)b * OH * OW;

    const float hr  = RR[ib + W + 2] - RR[ib + W + 1];
    const float hz  = ZZ[ib + 2 * W + 1] - ZZ[ib + W + 1];
    const float hr2 = hr * hr, hz2 = hz * hz;
    const float s   = -2.0f * (hr2 + hz2) / (hr2 * hz2);

    // Per-column folded coefficients: c4[t] over the 4 owned cols c0..c0+3
    const int c0 = 4 * l;
    float4 c4[9];
    {
        float4 invr;
        invr.x = 1.0f / RR[ib + W + (c0 + 1)];
        invr.y = 1.0f / RR[ib + W + (c0 + 2)];
        invr.z = 1.0f / RR[ib + W + (c0 + 3)];
        invr.w = 1.0f / RR[ib + W + ((c0 + 4 < W) ? (c0 + 4) : (W - 1))];
        const float* kl = KL + b * 9;
        const float* kd = KD + b * 9;
#pragma unroll
        for (int t = 0; t < 9; ++t) {
            const float a = kl[t] * s, d = kd[t] * s;
            c4[t].x = fmaf(d, invr.x, a);
            c4[t].y = fmaf(d, invr.y, a);
            c4[t].z = fmaf(d, invr.z, a);
            c4[t].w = fmaf(d, invr.w, a);
        }
    }

    // Prologue: rolling pred rows g0..g0+2 (pa,pb,pc) + shfl halos
    const int g0 = o0 - 1;
    float4 pa = make_float4(0.f, 0.f, 0.f, 0.f), pb, pc;
    if (g0 >= 0) pa = *(const float4*)(predb + (size_t)g0 * W + c0);
    pb = *(const float4*)(predb + (size_t)(g0 + 1) * W + c0);
    pc = *(const float4*)(predb + (size_t)(g0 + 2) * W + c0);
    float nxa = __shfl(pa.x, l + 1, 64), nya = __shfl(pa.y, l + 1, 64);
    float nxb = __shfl(pb.x, l + 1, 64), nyb = __shfl(pb.y, l + 1, 64);

    float4 ghA = make_float4(0.f, 0.f, 0.f, 0.f);
    float4 ghB = make_float4(0.f, 0.f, 0.f, 0.f);
    float2 rc0 = make_float2(0.f, 0.f), rc1 = make_float2(0.f, 0.f);
    float acc = 0.0f;

    for (int g = g0; g <= o1; ++g) {
        // --- prefetch pred row g+3 (consumed next iteration as pc) ---
        float4 pn = make_float4(0.f, 0.f, 0.f, 0.f);
        const int rowp = g + 3;
        if (rowp < H && rowp <= o1 + 2)
            pn = *(const float4*)(predb + (size_t)rowp * W + c0);

        // --- prefetch rhs row g (consumed next iteration at emit i=g) ---
        float2 rn0 = make_float2(0.f, 0.f), rn1 = make_float2(0.f, 0.f);
        if (g >= o0 && g < o1) {
            const float* rrow = rhsb + (size_t)g * OW + c0;
            rn0 = *(const float2*)rrow;
            if (c0 + 2 < OW) rn1 = *(const float2*)(rrow + 2);
        }

        // --- halos for the row newly in position c (loaded last iter) ---
        const float nxc = __shfl(pc.x, l + 1, 64);
        const float nyc = __shfl(pc.y, l + 1, 64);

        // --- GS_ope row g (zero outside [0,OH): SAME padding) ---
        float4 gs = make_float4(0.f, 0.f, 0.f, 0.f);
        if ((unsigned)g < (unsigned)OH) {
#define ROWC(p, nx, ny, t0)                                              \
            gs.x = fmaf(p.x, c4[t0].x, fmaf(p.y, c4[t0+1].x, fmaf(p.z, c4[t0+2].x, gs.x))); \
            gs.y = fmaf(p.y, c4[t0].y, fmaf(p.z, c4[t0+1].y, fmaf(p.w, c4[t0+2].y, gs.y))); \
            gs.z = fmaf(p.z, c4[t0].z, fmaf(p.w, c4[t0+1].z, fmaf(nx,  c4[t0+2].z, gs.z))); \
            gs.w = fmaf(p.w, c4[t0].w, fmaf(nx,  c4[t0+1].w, fmaf(ny,  c4[t0+2].w, gs.w)));
            ROWC(pa, nxa, nya, 0)
            ROWC(pb, nxb, nyb, 3)
            ROWC(pc, nxc, nyc, 6)
#undef ROWC
            if (l == 63) { gs.z = 0.f; gs.w = 0.f; }   // cols 254,255 out of range
        }

        // --- horizontal [1,2,1] ---
        float up = __shfl(gs.w, l - 1, 64);
        const float dn = __shfl(gs.x, l + 1, 64);     // lane 63: garbage, unused
        if (l == 0) up = 0.f;
        float4 gh;
        gh.x = fmaf(2.f, gs.x, up   + gs.y);
        gh.y = fmaf(2.f, gs.y, gs.x + gs.z);
        gh.z = fmaf(2.f, gs.z, gs.y + gs.w);
        gh.w = fmaf(2.f, gs.w, gs.z + dn);

        // --- vertical [1,2,1]/16, emit row i = g-1, MSE accumulate ---
        const int i = g - 1;
        if (i >= o0 && i < o1) {
            const float smx = (ghA.x + 2.f * ghB.x + gh.x) * 0.0625f;
            const float smy = (ghA.y + 2.f * ghB.y + gh.y) * 0.0625f;
            const float smz = (ghA.z + 2.f * ghB.z + gh.z) * 0.0625f;
            const float smw = (ghA.w + 2.f * ghB.w + gh.w) * 0.0625f;
            const float dx = smx - rc0.x;
            const float dy = smy - rc0.y;
            float dz = smz - rc1.x;
            float dw = smw - rc1.y;
            if (c0 + 2 >= OW) { dz = 0.f; dw = 0.f; }   // lane 63 tail cols
            acc = fmaf(dx, dx, acc);
            acc = fmaf(dy, dy, acc);
            acc = fmaf(dz, dz, acc);
            acc = fmaf(dw, dw, acc);
        }

        // --- roll ---
        pa = pb; pb = pc; pc = pn;
        nxa = nxb; nya = nyb; nxb = nxc; nyb = nyc;
        ghA = ghB; ghB = gh;
        rc0 = rn0; rc1 = rn1;
    }

    // wave reduce -> block reduce -> one atomic per block
#pragma unroll
    for (int off = 32; off > 0; off >>= 1)
        acc += __shfl_down(acc, off, 64);
    __shared__ float wsum[4];
    if (l == 0) wsum[wv] = acc;
    __syncthreads();
    if (tid == 0) {
        const float t = (wsum[0] + wsum[1]) + (wsum[2] + wsum[3]);
        atomicAdd(out, t * inv_n);
    }
}

extern "C" void kernel_launch(void* const* d_in, const int* in_sizes, int n_in,
                              void* d_out, int out_size, void* d_ws, size_t ws_size,
                              hipStream_t stream) {
    const float* pred = (const float*)d_in[0];
    const float* rhs  = (const float*)d_in[1];
    const float* KL   = (const float*)d_in[2];
    const float* KD   = (const float*)d_in[3];
    const float* RR   = (const float*)d_in[4];
    const float* ZZ   = (const float*)d_in[5];
    // d_in[6] = Gauss kernel [[1,2,1],[2,4,2],[1,2,1]]/16 — hardcoded, separable
    float* out = (float*)d_out;

    const int B = in_sizes[2] / 9;   // 256
    const float inv_n = 1.0f / ((float)B * 254.0f * 254.0f);

    hipMemsetAsync(out, 0, sizeof(float), stream);
    pde_loss_kernel<<<dim3(B * 8), dim3(256), 0, stream>>>(pred, rhs, KL, KD, RR, ZZ, out, inv_n);
}